// Round 6
// baseline (3047.123 us; speedup 1.0000x reference)
//
#include <hip/hip_runtime.h>
#include <hip/hip_cooperative_groups.h>

namespace cg = cooperative_groups;

// ---------------------------------------------------------------------------
// GenomeDecoder, R8: cooperative kernel with grid == chain width (16 blocks,
// 512 thr) -> ZERO spinner blocks (R5 lesson: 112 spinners during the 650us
// chain generated 660MB of coherent poll traffic and 2x'd the chain).
//   per block b: [prepm 64-row slice (LDS-tiled matmul, R3 lesson: never
//   latency-chain it) ; embed_b ; transformer_b x2 layers ALL in LDS ;
//   latent_b ; gi0_b]  -> ONE grid.sync ->  chain (R4 body, unchanged math).
// Epilogue GEMM needs full-chip fp32 width -> separate wide launch.
// 2 launches total (vs 8 in R4 at ~45-50us/boundary).
// Chain math unchanged: int8 M (per-row scale) x int8 h broadcast via
// mfma_i32_16x16x64_i8, parity-split gates, exact int32 accumulate.
// ---------------------------------------------------------------------------

typedef unsigned int uint_t;
typedef int v4i __attribute__((ext_vector_type(4)));

// ---- workspace layout (4-byte slot indices) ----
static constexpr size_t WS_CV   = 606208;   // 1024 fused-bias consts
static constexpr size_t WS_MS   = 607232;   // 1024 per-row scales
static constexpr size_t WS_M8   = 608256;   // 1024*64 dwords packed int8 M
static constexpr size_t WS_HSEQ = 673792;   // 1028*16*256 floats

__device__ inline float sigf(float x){
    return __builtin_amdgcn_rcpf(1.0f + __builtin_amdgcn_exp2f(-1.442695041f*x));
}
__device__ inline float tanh_fast(float x){
    return 1.0f - 2.0f*__builtin_amdgcn_rcpf(1.0f + __builtin_amdgcn_exp2f(2.885390082f*x));
}

// ======================= front + chain (cooperative, 16 blocks) ============

__global__ __launch_bounds__(512) void k_fc(
    const float* gs, const float* eW, const float* eb,
    const float* qkvW, const float* qkvb,
    const float* aoW, const float* aob,
    const float* g1, const float* b1, const float* g2, const float* b2v,
    const float* W1, const float* fb1, const float* W2, const float* fb2,
    const float* Wih, const float* bih, const float* Whh, const float* bhh,
    const float* outW, const float* outb,
    float* ws)
{
    __shared__ float smf[33536];              // 131 KB aliased staging
    __shared__ signed char h8[2][256];        // chain h double-buffer
    // prep aliases:
    float* wih = smf;                         // [64][256]
    float* ow  = smf + 16384;                 // [64][256] k-tile
    // transformer aliases (prep completes first):
    float* h    = smf;                        // [16][256]
    float* qkv  = smf + 4096;                 // [16][772] padded
    float* ao   = smf + 16448;                // [16][256]
    float* f1   = smf + 20544;                // [2][1024]
    float* hx   = smf + 22592;                // [2][256]
    float* red  = smf + 23104;                // [2][256]
    float* sc4  = smf + 23616;                // [4][16][16]
    float* lat  = smf + 24640;                // [256]
    float* gi0  = smf + 32768;                // [768] survives prep (outside)

    cg::grid_group grid = cg::this_grid();
    int tid = threadIdx.x;
    int b   = blockIdx.x;

    // ================= P: prepm, rows [64b, 64b+64) ========================
    {
        int r0 = b*64;
        int rg = tid>>5, cg = tid&31;         // 16 row-groups x 32 col-groups
        float acc[4][8];
        float ob8[8];
#pragma unroll
        for(int j=0;j<8;++j) ob8[j] = outb[cg*8+j];

        if(r0 >= 768){
            // rows 768..1023: m = Whh[r-256][c]
#pragma unroll
            for(int i=0;i<4;++i){
                int r = r0 + rg*4 + i;
                float4 v0 = *(const float4*)&Whh[(size_t)(r-256)*256 + cg*8];
                float4 v1 = *(const float4*)&Whh[(size_t)(r-256)*256 + cg*8 + 4];
                acc[i][0]=v0.x; acc[i][1]=v0.y; acc[i][2]=v0.z; acc[i][3]=v0.w;
                acc[i][4]=v1.x; acc[i][5]=v1.y; acc[i][6]=v1.z; acc[i][7]=v1.w;
            }
        } else {
            // A = Wih[r0..r0+64) @ outW, LDS-tiled
            for(int u=tid; u<4096; u+=512)
                ((float4*)wih)[u] = ((const float4*)(Wih + (size_t)r0*256))[u];
#pragma unroll
            for(int i=0;i<4;++i)
#pragma unroll
                for(int j=0;j<8;++j) acc[i][j]=0.f;
            for(int kt=0; kt<4; ++kt){
                __syncthreads();
                for(int u=tid; u<4096; u+=512)
                    ((float4*)ow)[u] = ((const float4*)(outW + (size_t)kt*64*256))[u];
                __syncthreads();
                for(int k=0;k<64;++k){
                    float w0 = wih[(rg*4+0)*256 + kt*64 + k];
                    float w1 = wih[(rg*4+1)*256 + kt*64 + k];
                    float w2 = wih[(rg*4+2)*256 + kt*64 + k];
                    float w3 = wih[(rg*4+3)*256 + kt*64 + k];
                    float4 o0 = *(const float4*)&ow[k*256 + cg*8];
                    float4 o1 = *(const float4*)&ow[k*256 + cg*8 + 4];
                    acc[0][0]+=w0*o0.x; acc[0][1]+=w0*o0.y; acc[0][2]+=w0*o0.z; acc[0][3]+=w0*o0.w;
                    acc[0][4]+=w0*o1.x; acc[0][5]+=w0*o1.y; acc[0][6]+=w0*o1.z; acc[0][7]+=w0*o1.w;
                    acc[1][0]+=w1*o0.x; acc[1][1]+=w1*o0.y; acc[1][2]+=w1*o0.z; acc[1][3]+=w1*o0.w;
                    acc[1][4]+=w1*o1.x; acc[1][5]+=w1*o1.y; acc[1][6]+=w1*o1.z; acc[1][7]+=w1*o1.w;
                    acc[2][0]+=w2*o0.x; acc[2][1]+=w2*o0.y; acc[2][2]+=w2*o0.z; acc[2][3]+=w2*o0.w;
                    acc[2][4]+=w2*o1.x; acc[2][5]+=w2*o1.y; acc[2][6]+=w2*o1.z; acc[2][7]+=w2*o1.w;
                    acc[3][0]+=w3*o0.x; acc[3][1]+=w3*o0.y; acc[3][2]+=w3*o0.z; acc[3][3]+=w3*o0.w;
                    acc[3][4]+=w3*o1.x; acc[3][5]+=w3*o1.y; acc[3][6]+=w3*o1.z; acc[3][7]+=w3*o1.w;
                }
            }
            if(r0 < 512){
#pragma unroll
                for(int i=0;i<4;++i){
                    int r = r0 + rg*4 + i;
                    float4 v0 = *(const float4*)&Whh[(size_t)r*256 + cg*8];
                    float4 v1 = *(const float4*)&Whh[(size_t)r*256 + cg*8 + 4];
                    acc[i][0]+=v0.x; acc[i][1]+=v0.y; acc[i][2]+=v0.z; acc[i][3]+=v0.w;
                    acc[i][4]+=v1.x; acc[i][5]+=v1.y; acc[i][6]+=v1.z; acc[i][7]+=v1.w;
                }
            }
        }
        // per-row: absmax (shfl over 32-lane cg group), CV dot, quantize
        uint_t* Mout = (uint_t*)ws;
#pragma unroll
        for(int i=0;i<4;++i){
            int r = r0 + rg*4 + i;
            float mx = 0.f;
#pragma unroll
            for(int j=0;j<8;++j) mx = fmaxf(mx, fabsf(acc[i][j]));
#pragma unroll
            for(int mk=1; mk<32; mk<<=1) mx = fmaxf(mx, __shfl_xor(mx, mk));
            float dot = 0.f;
            if(r < 768){
#pragma unroll
                for(int j=0;j<8;++j) dot += wih[(rg*4+i)*256 + cg*8 + j]*ob8[j];
#pragma unroll
                for(int mk=1; mk<32; mk<<=1) dot += __shfl_xor(dot, mk);
            }
            if(cg==0){
                ws[WS_MS + r] = mx>0.f ? mx*(1.0f/(127.0f*127.0f)) : 0.0f;
                float cv;
                if(r<512)       cv = dot + bih[r] + bhh[r];
                else if(r<768)  cv = dot + bih[r];
                else            cv = bhh[r-256];
                ws[WS_CV + r] = cv;
            }
            float inv = mx>0.f ? 127.0f/mx : 0.0f;
            int q0 = __float2int_rn(acc[i][0]*inv), q1 = __float2int_rn(acc[i][1]*inv);
            int q2 = __float2int_rn(acc[i][2]*inv), q3 = __float2int_rn(acc[i][3]*inv);
            int q4 = __float2int_rn(acc[i][4]*inv), q5 = __float2int_rn(acc[i][5]*inv);
            int q6 = __float2int_rn(acc[i][6]*inv), q7 = __float2int_rn(acc[i][7]*inv);
            uint_t d0 = (q0&255) | ((q1&255)<<8) | ((q2&255)<<16) | ((uint_t)(q3&255)<<24);
            uint_t d1 = (q4&255) | ((q5&255)<<8) | ((q6&255)<<16) | ((uint_t)(q7&255)<<24);
            Mout[WS_M8 + (size_t)r*64 + cg*2    ] = d0;
            Mout[WS_M8 + (size_t)r*64 + cg*2 + 1] = d1;
        }
    }
    __syncthreads();   // prep LDS reads done before transformer overwrites

    // ================= E: embed =================
    for(int u=tid; u<4096; u+=512){
        int s=u>>8, i=u&255;
        const float* g = gs + (b*16+s)*16;
        float a = eb[i];
#pragma unroll
        for(int d=0;d<16;++d) a += g[d]*eW[i*16+d];
        h[s*256+i] = a;
    }
    __syncthreads();

    // ================= transformer, 2 layers, all-LDS =================
    for(int l=0;l<2;++l){
        // qkv: 768 rows over 512 threads
        for(int j=tid; j<768; j+=512){
            const float* wr = qkvW + (size_t)(l*768+j)*256;
            float bias = qkvb[l*768+j];
            float acc[16];
#pragma unroll
            for(int s=0;s<16;++s) acc[s]=bias;
            for(int k=0;k<256;k+=4){
                float4 w4 = *(const float4*)(wr+k);
#pragma unroll
                for(int s=0;s<16;++s){
                    float4 h4 = *(const float4*)&h[s*256+k];
                    acc[s] += w4.x*h4.x + w4.y*h4.y + w4.z*h4.z + w4.w*h4.w;
                }
            }
#pragma unroll
            for(int s=0;s<16;++s) qkv[s*772 + j] = acc[s];
        }
        __syncthreads();

        // scores, all 4 heads
        for(int u=tid; u<1024; u+=512){
            int hh=u>>8, s=(u>>4)&15, t=u&15;
            float a=0.f;
            for(int d=0; d<64; d+=4){
                float4 q4 = *(const float4*)&qkv[s*772 + hh*64 + d];
                float4 k4 = *(const float4*)&qkv[t*772 + 256 + hh*64 + d];
                a += q4.x*k4.x + q4.y*k4.y + q4.z*k4.z + q4.w*k4.w;
            }
            sc4[hh*256 + s*16 + t] = a*0.125f;
        }
        __syncthreads();
        if(tid<64){
            int hh=tid>>4, r=tid&15;
            float* sr = sc4 + hh*256 + r*16;
            float m=-1e30f;
#pragma unroll
            for(int tt=0;tt<16;++tt) m=fmaxf(m,sr[tt]);
            float e[16]; float sum=0.f;
#pragma unroll
            for(int tt=0;tt<16;++tt){ e[tt]=__expf(sr[tt]-m); sum+=e[tt]; }
            float inv=1.0f/sum;
#pragma unroll
            for(int tt=0;tt<16;++tt) sr[tt]=e[tt]*inv;
        }
        __syncthreads();
        // AV
        for(int u=tid; u<4096; u+=512){
            int hh=u>>10, s=(u>>6)&15, d=u&63;
            float o=0.f;
#pragma unroll
            for(int t2=0;t2<16;++t2) o += sc4[hh*256+s*16+t2]*qkv[t2*772 + 512 + hh*64 + d];
            ao[s*256 + hh*64 + d] = o;
        }
        __syncthreads();

        // ao-matvec + LN1 + ffn1 + ffn2 + LN2, token pairs
        for(int it=0; it<8; ++it){
            int tk = tid>>8, i = tid&255, s = it*2+tk;
            const float* wr = aoW + (size_t)(l*256+i)*256;
            float acc = aob[l*256+i];
            for(int k=0;k<256;k+=4){
                float4 w4 = *(const float4*)(wr+k);
                float4 a4 = *(const float4*)&ao[s*256+k];
                acc += w4.x*a4.x + w4.y*a4.y + w4.z*a4.z + w4.w*a4.w;
            }
            float x = h[s*256+i] + acc;
            red[tk*256+i]=x; __syncthreads();
            for(int off=128;off>0;off>>=1){ if(i<off) red[tk*256+i]+=red[tk*256+i+off]; __syncthreads(); }
            float mn = red[tk*256]*(1.0f/256.0f); __syncthreads();
            float d = x-mn;
            red[tk*256+i]=d*d; __syncthreads();
            for(int off=128;off>0;off>>=1){ if(i<off) red[tk*256+i]+=red[tk*256+i+off]; __syncthreads(); }
            float vv = red[tk*256]*(1.0f/256.0f);
            float h1 = (d / sqrtf(vv+1e-5f))*g1[l*256+i] + b1[l*256+i];
            __syncthreads();
            hx[tk*256+i] = h1;
            __syncthreads();
#pragma unroll
            for(int jj=0;jj<4;++jj){
                int j = jj*256 + i;
                const float* w1r = W1 + (size_t)(l*1024+j)*256;
                float a1 = fb1[l*1024+j];
                for(int k=0;k<256;k+=4){
                    float4 w4 = *(const float4*)(w1r+k);
                    float4 h4 = *(const float4*)&hx[tk*256+k];
                    a1 += w4.x*h4.x + w4.y*h4.y + w4.z*h4.z + w4.w*h4.w;
                }
                f1[tk*1024+j] = fmaxf(a1, 0.0f);
            }
            __syncthreads();
            const float* w2r = W2 + (size_t)(l*256+i)*1024;
            float a2 = fb2[l*256+i];
            for(int k=0;k<1024;k+=4){
                float4 w4 = *(const float4*)(w2r+k);
                float4 h4 = *(const float4*)&f1[tk*1024+k];
                a2 += w4.x*h4.x + w4.y*h4.y + w4.z*h4.z + w4.w*h4.w;
            }
            float x2 = h1 + a2;
            red[tk*256+i]=x2; __syncthreads();
            for(int off=128;off>0;off>>=1){ if(i<off) red[tk*256+i]+=red[tk*256+i+off]; __syncthreads(); }
            float mn2 = red[tk*256]*(1.0f/256.0f); __syncthreads();
            float d2 = x2-mn2;
            red[tk*256+i]=d2*d2; __syncthreads();
            for(int off=128;off>0;off>>=1){ if(i<off) red[tk*256+i]+=red[tk*256+i+off]; __syncthreads(); }
            float vv2 = red[tk*256]*(1.0f/256.0f);
            float y2 = d2 / sqrtf(vv2+1e-5f);
            h[s*256+i] = y2*g2[l*256+i] + b2v[l*256+i];
            __syncthreads();
        }
    }

    // ================= latent + gi0 (LDS) =================
    if(tid<256){
        float a=0.f;
#pragma unroll
        for(int s=0;s<16;++s) a += h[s*256+tid];
        lat[tid] = a*(1.0f/16.0f);
    }
    __syncthreads();
    for(int j=tid; j<768; j+=512){
        const float* wr = Wih + (size_t)j*256;
        float a = bih[j];
        for(int k=0;k<256;k+=4){
            float4 w4=*(const float4*)(wr+k);
            float4 l4=*(const float4*)&lat[k];
            a += w4.x*l4.x + w4.y*l4.y + w4.z*l4.z + w4.w*l4.w;
        }
        gi0[j] = a;
    }

    grid.sync();        // all blocks' M8/CV/MS visible; own gi0 LDS synced

    // ================= CH: sequential GRU chain (R4 body) =================
    {
        int ln  = tid & 63;
        int w   = tid >> 6;
        int col = ln & 15;
        int grp = ln >> 4;
        int par = grp & 1;
        int ge  = w*32 + par*16 + col;

        const uint_t* Mdw = (const uint_t*)ws + WS_M8;
        v4i wf[8][4];
#pragma unroll
        for(int s=0;s<4;++s){
#pragma unroll
            for(int half=0; half<2; ++half){
                int f = s*2 + half;
                int row = s*256 + w*32 + half*16 + col;
                const uint_t* src = Mdw + (size_t)row*64 + grp*4;
#pragma unroll
                for(int kt=0;kt<4;++kt)
                    wf[f][kt] = *(const v4i*)(src + kt*16);
            }
        }
        float Cs[4], MSs[4];
#pragma unroll
        for(int s=0;s<4;++s){
            int row = s*256 + ge;
            Cs[s]  = ws[WS_CV + row];
            MSs[s] = ws[WS_MS + row];
        }

        float r0g = sigf(gi0[ge]     + bhh[ge]);
        float z0g = sigf(gi0[256+ge] + bhh[256+ge]);
        float n0g = tanh_fast(gi0[512+ge] + r0g*bhh[512+ge]);
        float hp = (1.0f-z0g)*n0g;

        float* hsp = ws + WS_HSEQ + (size_t)b*256;
        if(grp < 2){
            h8[0][w*32 + (ln&31)] = (signed char)__float2int_rn(hp*127.0f);
            hsp[w*32 + (ln&31)] = hp;
        }
        asm volatile("s_waitcnt lgkmcnt(0)" ::: "memory");
        __builtin_amdgcn_s_barrier();
        asm volatile("" ::: "memory");

        const v4i vzero = {0,0,0,0};
        int po = 0;
        for(int t=1; t<1028; ++t){
            hsp += 4096;
            v4i af[4];
#pragma unroll
            for(int kt=0;kt<4;++kt)
                af[kt] = *(const v4i*)&h8[po][kt*64 + grp*16];
            v4i acc[8];
#pragma unroll
            for(int f=0;f<8;++f){
                acc[f] = __builtin_amdgcn_mfma_i32_16x16x64_i8(af[0], wf[f][0], vzero, 0,0,0);
#pragma unroll
                for(int kt=1;kt<4;++kt)
                    acc[f] = __builtin_amdgcn_mfma_i32_16x16x64_i8(af[kt], wf[f][kt], acc[f], 0,0,0);
            }
            int a_r = par ? acc[1][0] : acc[0][0];
            int a_z = par ? acc[3][0] : acc[2][0];
            int a_n = par ? acc[5][0] : acc[4][0];
            int a_h = par ? acc[7][0] : acc[6][0];
            float yr = MSs[0]*(float)a_r + Cs[0];
            float yz = MSs[1]*(float)a_z + Cs[1];
            float yn = MSs[2]*(float)a_n + Cs[2];
            float yh = MSs[3]*(float)a_h + Cs[3];
            float rr = sigf(yr);
            float zz = sigf(yz);
            float nn = tanh_fast(yn + rr*yh);
            hp = (1.0f-zz)*nn + zz*hp;
            if(grp < 2){
                h8[po^1][w*32 + (ln&31)] = (signed char)__float2int_rn(hp*127.0f);
                hsp[w*32 + (ln&31)] = hp;
            }
            asm volatile("s_waitcnt lgkmcnt(0)" ::: "memory");
            __builtin_amdgcn_s_barrier();
            asm volatile("" ::: "memory");
            po ^= 1;
        }
    }
}

// ======================= epilogue GEMM (wide launch) =======================
__global__ __launch_bounds__(256) void k_epi(const float* outW, const float* outb,
                                             const float* ws, float* out){
    __shared__ float ht[16][256];
    int t = blockIdx.x, j = threadIdx.x;
    for(int idx=j; idx<4096; idx+=256)
        ht[idx>>8][idx&255] = ws[WS_HSEQ + (size_t)t*4096 + idx];
    __syncthreads();
    const float* wr = outW + (size_t)j*256;
    float bias = outb[j];
    float acc[16];
#pragma unroll
    for(int bb=0;bb<16;++bb) acc[bb]=bias;
    for(int k=0;k<256;k+=4){
        float4 w4 = *(const float4*)(wr+k);
#pragma unroll
        for(int bb=0;bb<16;++bb)
            acc[bb] += w4.x*ht[bb][k]+w4.y*ht[bb][k+1]+w4.z*ht[bb][k+2]+w4.w*ht[bb][k+3];
    }
#pragma unroll
    for(int bb=0;bb<16;++bb)
        out[(size_t)bb*263168 + (size_t)t*256 + j] = acc[bb];
}

// ======================= launch ============================================

extern "C" void kernel_launch(void* const* d_in, const int* in_sizes, int n_in,
                              void* d_out, int out_size, void* d_ws, size_t ws_size,
                              hipStream_t stream){
    const float* gs   = (const float*)d_in[0];
    const float* eW   = (const float*)d_in[1];
    const float* eb   = (const float*)d_in[2];
    const float* qkvW = (const float*)d_in[3];
    const float* qkvb = (const float*)d_in[4];
    const float* aoW  = (const float*)d_in[5];
    const float* aob  = (const float*)d_in[6];
    const float* g1   = (const float*)d_in[7];
    const float* b1   = (const float*)d_in[8];
    const float* g2   = (const float*)d_in[9];
    const float* b2   = (const float*)d_in[10];
    const float* W1   = (const float*)d_in[11];
    const float* fb1  = (const float*)d_in[12];
    const float* W2   = (const float*)d_in[13];
    const float* fb2  = (const float*)d_in[14];
    const float* Wih  = (const float*)d_in[15];
    const float* Whh  = (const float*)d_in[16];
    const float* bih  = (const float*)d_in[17];
    const float* bhh  = (const float*)d_in[18];
    const float* outW = (const float*)d_in[19];
    const float* outb = (const float*)d_in[20];
    float* ws  = (float*)d_ws;
    float* out = (float*)d_out;

    void* args[] = {
        (void*)&gs, (void*)&eW, (void*)&eb, (void*)&qkvW, (void*)&qkvb,
        (void*)&aoW, (void*)&aob, (void*)&g1, (void*)&b1, (void*)&g2,
        (void*)&b2, (void*)&W1, (void*)&fb1, (void*)&W2, (void*)&fb2,
        (void*)&Wih, (void*)&bih, (void*)&Whh, (void*)&bhh, (void*)&outW,
        (void*)&outb, (void*)&ws
    };
    hipLaunchCooperativeKernel((const void*)k_fc, dim3(16), dim3(512),
                               args, 0, stream);
    k_epi<<<1028,256,0,stream>>>(outW,outb,ws,out);
}

// Round 7
// 1529.572 us; speedup vs baseline: 1.9921x; 1.9921x over previous
//
#include <hip/hip_runtime.h>
#include <hip/hip_cooperative_groups.h>

namespace cg = cooperative_groups;

// ---------------------------------------------------------------------------
// GenomeDecoder, R9: proven-pieces-only assembly.
//   L1: cooperative WIDE front (128 blk x 512, R5's validated front stages:
//       E -> [qkv+attn || prepm] -> F -> qkv+attn -> F -> lat+gi0, 5 cheap
//       grid.syncs, NO chain inside -> no spinners, no 16-CU serial front).
//   L2: k_chain (16 blk, R4 body: int8 M x int8 h broadcast via
//       mfma_i32_16x16x64_i8, parity-split gates, exact int32).
//   L3: k_epi (1028 blk wide fp32 GEMM).
// 3 launches / 2 boundaries (~45-70us each on this harness).
// R5 lesson: spinners during the 650us chain cost 2x chain + 660MB traffic.
// R6 lesson: front on 16 blocks is a 2.2ms latency chain.  R3 lesson: same
// at 32 blocks.  Front must stay >=128 blocks; only the chain tolerates 16.
// ---------------------------------------------------------------------------

typedef unsigned int uint_t;
typedef int v4i __attribute__((ext_vector_type(4)));

// ---- workspace layout (4-byte slot indices) ----
static constexpr size_t WS_HB   = 0;        // 16*16*256
static constexpr size_t WS_AO   = 262144;   // 16*16*256
static constexpr size_t WS_GI0  = 593920;   // 16*768
static constexpr size_t WS_CV   = 606208;   // 1024 fused-bias consts
static constexpr size_t WS_MS   = 607232;   // 1024 per-row scales
static constexpr size_t WS_M8   = 608256;   // 1024*64 dwords packed int8 M
static constexpr size_t WS_HSEQ = 673792;   // 1028*16*256 floats

__device__ inline float sigf(float x){
    return __builtin_amdgcn_rcpf(1.0f + __builtin_amdgcn_exp2f(-1.442695041f*x));
}
__device__ inline float tanh_fast(float x){
    return 1.0f - 2.0f*__builtin_amdgcn_rcpf(1.0f + __builtin_amdgcn_exp2f(2.885390082f*x));
}

// ======================= cooperative wide front ============================

__global__ __launch_bounds__(512) void k_front(
    const float* gs, const float* eW, const float* eb,
    const float* qkvW, const float* qkvb,
    const float* aoW, const float* aob,
    const float* g1, const float* b1, const float* g2, const float* b2v,
    const float* W1, const float* fb1, const float* W2, const float* fb2,
    const float* Wih, const float* bih, const float* Whh, const float* bhh,
    const float* outW, const float* outb,
    float* ws)
{
    __shared__ float s_h[16][256];            // 16 KB staging
    __shared__ float s_qkv[3][16][64];        // 12 KB q/k/v
    __shared__ float s_sc[16][16];            // 1 KB scores / lat / prepm q8
    __shared__ float s_f1[2][1024];           // 8 KB F1 rows / prepm wrow
    __shared__ float s_red[2][256];           // 2 KB LN partials / prepm red

    cg::grid_group grid = cg::this_grid();
    int tid = threadIdx.x;
    int bx  = blockIdx.x;

    // ================= E: embed (2 tokens/block) =================
    {
        int bs = bx*2 + (tid>>8);
        int i  = tid & 255;
        const float* g = gs + bs*16;
        float acc = eb[i];
#pragma unroll
        for(int d=0; d<16; ++d) acc += g[d]*eW[i*16+d];
        ws[WS_HB + (size_t)bs*256 + i] = acc;
    }
    grid.sync();                                            // 1

    for(int l=0; l<2; ++l){
        if(bx < 64){
            // ============ A: qkv + attention, (b,head) ============
            int b = bx>>2, hh = bx&3;
            for(int u=tid; u<4096; u+=512)
                s_h[u>>8][u&255] = ws[WS_HB + (size_t)(b*16+(u>>8))*256 + (u&255)];
            __syncthreads();
            if(tid<192){
                int p = tid>>6, d = tid&63;           // p: 0=q 1=k 2=v
                int row = l*768 + p*256 + hh*64 + d;
                const float* wr = qkvW + (size_t)row*256;
                float bias = qkvb[row];
                float acc[16];
#pragma unroll
                for(int s=0;s<16;++s) acc[s]=bias;
                for(int k=0;k<256;k+=4){
                    float4 w4 = *(const float4*)(wr+k);
#pragma unroll
                    for(int s=0;s<16;++s){
                        float4 h4 = *(const float4*)&s_h[s][k];
                        acc[s] += w4.x*h4.x + w4.y*h4.y + w4.z*h4.z + w4.w*h4.w;
                    }
                }
#pragma unroll
                for(int s=0;s<16;++s) s_qkv[p][s][d] = acc[s];
            }
            __syncthreads();
            if(tid<256){
                int s = tid>>4, t = tid&15;
                float a=0.f;
#pragma unroll
                for(int d=0; d<64; ++d) a += s_qkv[0][s][d]*s_qkv[1][t][d];
                s_sc[s][t] = a*0.125f;
            }
            __syncthreads();
            if(tid<16){
                int r=tid;
                float m=-1e30f;
#pragma unroll
                for(int tt=0;tt<16;++tt) m=fmaxf(m,s_sc[r][tt]);
                float e[16]; float sum=0.f;
#pragma unroll
                for(int tt=0;tt<16;++tt){ e[tt]=__expf(s_sc[r][tt]-m); sum+=e[tt]; }
                float inv=1.0f/sum;
#pragma unroll
                for(int tt=0;tt<16;++tt) s_sc[r][tt]=e[tt]*inv;
            }
            __syncthreads();
            for(int u=tid; u<1024; u+=512){
                int s=u>>6, d=u&63;
                float o=0.f;
#pragma unroll
                for(int t2=0;t2<16;++t2) o += s_sc[s][t2]*s_qkv[2][t2][d];
                ws[WS_AO + (size_t)(b*16+s)*256 + hh*64 + d] = o;
            }
        } else if(l==0){
            // ============ P: prepm, 16 rows per block ============
            int pb = bx - 64;                         // 0..63
            float* wrow = &s_f1[0][0];                // [2][256]
            float* redf = &s_red[0][0];               // 32 slots
            signed char* q8 = (signed char*)&s_sc[0][0]; // 512 B
            int rh = tid>>8, c = tid&255, wv = tid>>6;
            for(int it=0; it<8; ++it){
                int r = pb*16 + it*2 + rh;
                bool hasA = (r < 768);
                wrow[rh*256+c] = hasA ? Wih[(size_t)r*256+c] : 0.0f;
                __syncthreads();
                float m;
                if(hasA){
                    float a = 0.f;
                    for(int k=0;k<256;++k) a += wrow[rh*256+k]*outW[(size_t)k*256+c];
                    if(r<512) a += Whh[(size_t)r*256+c];
                    m = a;
                } else {
                    m = Whh[(size_t)(r-256)*256+c];
                }
                float pv = wrow[rh*256+c]*outb[c];
                for(int mk=1; mk<64; mk<<=1) pv += __shfl_xor(pv, mk);
                if((tid&63)==0) redf[wv] = pv;
                __syncthreads();
                if(c==0){
                    float cs = redf[rh*4+0]+redf[rh*4+1]+redf[rh*4+2]+redf[rh*4+3];
                    float cv;
                    if(r<512)       cv = cs + bih[r] + bhh[r];
                    else if(r<768)  cv = cs + bih[r];
                    else            cv = bhh[r-256];
                    ws[WS_CV + r] = cv;
                }
                float av = fabsf(m);
                for(int mk=1; mk<64; mk<<=1) av = fmaxf(av, __shfl_xor(av, mk));
                if((tid&63)==0) redf[16+wv] = av;
                __syncthreads();
                float rowmax = fmaxf(fmaxf(redf[16+rh*4],redf[17+rh*4]),
                                     fmaxf(redf[18+rh*4],redf[19+rh*4]));
                float inv = rowmax>0.f ? 127.0f/rowmax : 0.0f;
                q8[rh*256+c] = (signed char)__float2int_rn(m*inv);
                if(c==0) ws[WS_MS + r] = rowmax>0.f ? rowmax*(1.0f/(127.0f*127.0f)) : 0.0f;
                __syncthreads();
                if(c<64){
                    uint_t u = ((uint_t)(unsigned char)q8[rh*256+4*c  ])
                             | ((uint_t)(unsigned char)q8[rh*256+4*c+1] << 8)
                             | ((uint_t)(unsigned char)q8[rh*256+4*c+2] << 16)
                             | ((uint_t)(unsigned char)q8[rh*256+4*c+3] << 24);
                    ((uint_t*)ws)[WS_M8 + (size_t)r*64 + c] = u;
                }
                __syncthreads();
            }
        }
        grid.sync();                                        // 2 / 4

        // ============ F: ao + LN1 + ffn1 + ffn2 + LN2 (2 tokens) ============
        {
            int tk = tid>>8, i = tid&255;
            int bs = bx*2 + tk;
            s_h[tk][i] = ws[WS_AO + (size_t)bs*256 + i];
            float hb = ws[WS_HB + (size_t)bs*256 + i];
            __syncthreads();
            const float* wr = aoW + (size_t)(l*256+i)*256;
            float acc = aob[l*256+i];
            for(int k=0;k<256;k+=4){
                float4 w4 = *(const float4*)(wr+k);
                float4 h4 = *(const float4*)&s_h[tk][k];
                acc += w4.x*h4.x + w4.y*h4.y + w4.z*h4.z + w4.w*h4.w;
            }
            float x = hb + acc;
            // LN1
            s_red[tk][i]=x; __syncthreads();
            for(int off=128;off>0;off>>=1){ if(i<off) s_red[tk][i]+=s_red[tk][i+off]; __syncthreads(); }
            float mn = s_red[tk][0]*(1.0f/256.0f); __syncthreads();
            float d = x-mn;
            s_red[tk][i]=d*d; __syncthreads();
            for(int off=128;off>0;off>>=1){ if(i<off) s_red[tk][i]+=s_red[tk][i+off]; __syncthreads(); }
            float vv = s_red[tk][0]*(1.0f/256.0f);
            float h1 = (d / sqrtf(vv+1e-5f))*g1[l*256+i] + b1[l*256+i];
            __syncthreads();
            s_h[2+tk][i] = h1;
            __syncthreads();
            // ffn1
#pragma unroll
            for(int jj=0;jj<4;++jj){
                int j = jj*256 + i;
                const float* w1r = W1 + (size_t)(l*1024+j)*256;
                float a1 = fb1[l*1024+j];
                for(int k=0;k<256;k+=4){
                    float4 w4 = *(const float4*)(w1r+k);
                    float4 h4 = *(const float4*)&s_h[2+tk][k];
                    a1 += w4.x*h4.x + w4.y*h4.y + w4.z*h4.z + w4.w*h4.w;
                }
                s_f1[tk][j] = fmaxf(a1, 0.0f);
            }
            __syncthreads();
            // ffn2
            const float* w2r = W2 + (size_t)(l*256+i)*1024;
            float a2 = fb2[l*256+i];
            for(int k=0;k<1024;k+=4){
                float4 w4 = *(const float4*)(w2r+k);
                float4 h4 = *(const float4*)&s_f1[tk][k];
                a2 += w4.x*h4.x + w4.y*h4.y + w4.z*h4.z + w4.w*h4.w;
            }
            float x2 = h1 + a2;
            // LN2
            s_red[tk][i]=x2; __syncthreads();
            for(int off=128;off>0;off>>=1){ if(i<off) s_red[tk][i]+=s_red[tk][i+off]; __syncthreads(); }
            float mn2 = s_red[tk][0]*(1.0f/256.0f); __syncthreads();
            float d2 = x2-mn2;
            s_red[tk][i]=d2*d2; __syncthreads();
            for(int off=128;off>0;off>>=1){ if(i<off) s_red[tk][i]+=s_red[tk][i+off]; __syncthreads(); }
            float vv2 = s_red[tk][0]*(1.0f/256.0f);
            float y2 = d2 / sqrtf(vv2+1e-5f);
            ws[WS_HB + (size_t)bs*256 + i] = y2*g2[l*256+i] + b2v[l*256+i];
        }
        grid.sync();                                        // 3 / 5
    }

    // ================= LG: latent mean + gi0 (blocks 0-15, then exit) ======
    if(bx < 16){
        float* lat = &s_sc[0][0];
        if(tid<256){
            float a=0.f;
#pragma unroll
            for(int s=0;s<16;++s) a += ws[WS_HB + (size_t)(bx*16+s)*256 + tid];
            lat[tid] = a*(1.0f/16.0f);
        }
        __syncthreads();
        for(int j=tid; j<768; j+=512){
            const float* wr = Wih + (size_t)j*256;
            float acc = bih[j];
            for(int k=0;k<256;k+=4){
                float4 w4=*(const float4*)(wr+k);
                float4 l4=*(const float4*)&lat[k];
                acc += w4.x*l4.x + w4.y*l4.y + w4.z*l4.z + w4.w*l4.w;
            }
            ws[WS_GI0 + (size_t)bx*768 + j] = acc;
        }
    }
}

// ======================= sequential GRU chain (R4 body) ====================
// 16 blocks, 512 thr = 8 waves.  Wave w owns h slice [w*32,w*32+32): 8
// B-fragments (4 gate slices x 2 halves) x 4 K-tiles of mfma_i32_16x16x64_i8;
// A = h broadcast to all 16 rows.  Parity-split gates (3 transcendentals).
// h double-buffered in LDS; raw s_barrier + lgkmcnt-only wait.

__global__ __launch_bounds__(512,2) void k_chain(const float* bhh, float* ws){
    __shared__ alignas(16) signed char h8[2][256];
    int tid = threadIdx.x;
    int b   = blockIdx.x;
    int l   = tid & 63;
    int w   = tid >> 6;
    int col = l & 15;
    int grp = l >> 4;
    int par = grp & 1;
    int ge  = w*32 + par*16 + col;

    const uint_t* Mdw = (const uint_t*)ws + WS_M8;
    v4i wf[8][4];
#pragma unroll
    for(int s=0;s<4;++s){
#pragma unroll
        for(int half=0; half<2; ++half){
            int f = s*2 + half;
            int row = s*256 + w*32 + half*16 + col;
            const uint_t* src = Mdw + (size_t)row*64 + grp*4;
#pragma unroll
            for(int kt=0;kt<4;++kt)
                wf[f][kt] = *(const v4i*)(src + kt*16);
        }
    }
    float Cs[4], MSs[4];
#pragma unroll
    for(int s=0;s<4;++s){
        int row = s*256 + ge;
        Cs[s]  = ws[WS_CV + row];
        MSs[s] = ws[WS_MS + row];
    }

    const float* gi = ws + WS_GI0 + (size_t)b*768;
    float r0 = sigf(gi[ge]     + bhh[ge]);
    float z0 = sigf(gi[256+ge] + bhh[256+ge]);
    float n0 = tanh_fast(gi[512+ge] + r0*bhh[512+ge]);
    float hp = (1.0f-z0)*n0;

    float* hsp = ws + WS_HSEQ + (size_t)b*256;
    if(grp < 2){
        h8[0][w*32 + (l&31)] = (signed char)__float2int_rn(hp*127.0f);
        hsp[w*32 + (l&31)] = hp;
    }
    asm volatile("s_waitcnt lgkmcnt(0)" ::: "memory");
    __builtin_amdgcn_s_barrier();
    asm volatile("" ::: "memory");

    const v4i vzero = {0,0,0,0};
    int po = 0;
    for(int t=1; t<1028; ++t){
        hsp += 4096;
        v4i af[4];
#pragma unroll
        for(int kt=0;kt<4;++kt)
            af[kt] = *(const v4i*)&h8[po][kt*64 + grp*16];
        v4i acc[8];
#pragma unroll
        for(int f=0;f<8;++f){
            acc[f] = __builtin_amdgcn_mfma_i32_16x16x64_i8(af[0], wf[f][0], vzero, 0,0,0);
#pragma unroll
            for(int kt=1;kt<4;++kt)
                acc[f] = __builtin_amdgcn_mfma_i32_16x16x64_i8(af[kt], wf[f][kt], acc[f], 0,0,0);
        }
        int a_r = par ? acc[1][0] : acc[0][0];
        int a_z = par ? acc[3][0] : acc[2][0];
        int a_n = par ? acc[5][0] : acc[4][0];
        int a_h = par ? acc[7][0] : acc[6][0];
        float yr = MSs[0]*(float)a_r + Cs[0];
        float yz = MSs[1]*(float)a_z + Cs[1];
        float yn = MSs[2]*(float)a_n + Cs[2];
        float yh = MSs[3]*(float)a_h + Cs[3];
        float rr = sigf(yr);
        float zz = sigf(yz);
        float nn = tanh_fast(yn + rr*yh);
        hp = (1.0f-zz)*nn + zz*hp;
        if(grp < 2){
            h8[po^1][w*32 + (l&31)] = (signed char)__float2int_rn(hp*127.0f);
            hsp[w*32 + (l&31)] = hp;
        }
        asm volatile("s_waitcnt lgkmcnt(0)" ::: "memory");
        __builtin_amdgcn_s_barrier();
        asm volatile("" ::: "memory");
        po ^= 1;
    }
}

// ======================= epilogue GEMM (wide) ==============================
__global__ __launch_bounds__(256) void k_epi(const float* outW, const float* outb,
                                             const float* ws, float* out){
    __shared__ float ht[16][256];
    int t = blockIdx.x, j = threadIdx.x;
    for(int idx=j; idx<4096; idx+=256)
        ht[idx>>8][idx&255] = ws[WS_HSEQ + (size_t)t*4096 + idx];
    __syncthreads();
    const float* wr = outW + (size_t)j*256;
    float bias = outb[j];
    float acc[16];
#pragma unroll
    for(int bb=0;bb<16;++bb) acc[bb]=bias;
    for(int k=0;k<256;k+=4){
        float4 w4 = *(const float4*)(wr+k);
#pragma unroll
        for(int bb=0;bb<16;++bb)
            acc[bb] += w4.x*ht[bb][k]+w4.y*ht[bb][k+1]+w4.z*ht[bb][k+2]+w4.w*ht[bb][k+3];
    }
#pragma unroll
    for(int bb=0;bb<16;++bb)
        out[(size_t)bb*263168 + (size_t)t*256 + j] = acc[bb];
}

// ======================= launch ============================================

extern "C" void kernel_launch(void* const* d_in, const int* in_sizes, int n_in,
                              void* d_out, int out_size, void* d_ws, size_t ws_size,
                              hipStream_t stream){
    const float* gs   = (const float*)d_in[0];
    const float* eW   = (const float*)d_in[1];
    const float* eb   = (const float*)d_in[2];
    const float* qkvW = (const float*)d_in[3];
    const float* qkvb = (const float*)d_in[4];
    const float* aoW  = (const float*)d_in[5];
    const float* aob  = (const float*)d_in[6];
    const float* g1   = (const float*)d_in[7];
    const float* b1   = (const float*)d_in[8];
    const float* g2   = (const float*)d_in[9];
    const float* b2   = (const float*)d_in[10];
    const float* W1   = (const float*)d_in[11];
    const float* fb1  = (const float*)d_in[12];
    const float* W2   = (const float*)d_in[13];
    const float* fb2  = (const float*)d_in[14];
    const float* Wih  = (const float*)d_in[15];
    const float* Whh  = (const float*)d_in[16];
    const float* bih  = (const float*)d_in[17];
    const float* bhh  = (const float*)d_in[18];
    const float* outW = (const float*)d_in[19];
    const float* outb = (const float*)d_in[20];
    float* ws  = (float*)d_ws;
    float* out = (float*)d_out;

    void* args[] = {
        (void*)&gs, (void*)&eW, (void*)&eb, (void*)&qkvW, (void*)&qkvb,
        (void*)&aoW, (void*)&aob, (void*)&g1, (void*)&b1, (void*)&g2,
        (void*)&b2, (void*)&W1, (void*)&fb1, (void*)&W2, (void*)&fb2,
        (void*)&Wih, (void*)&bih, (void*)&Whh, (void*)&bhh, (void*)&outW,
        (void*)&outb, (void*)&ws
    };
    hipLaunchCooperativeKernel((const void*)k_front, dim3(128), dim3(512),
                               args, 0, stream);
    k_chain<<<16,512,0,stream>>>(bhh,ws);
    k_epi  <<<1028,256,0,stream>>>(outW,outb,ws,out);
}

// Round 8
// 1446.174 us; speedup vs baseline: 2.1070x; 1.0577x over previous
//
#include <hip/hip_runtime.h>

// ---------------------------------------------------------------------------
// GenomeDecoder, R10: co-resident front WITHOUT cg::grid.sync.
// Evidence chain: R5/R7 showed cg::grid.sync at 128 blocks hot-spins with
// device-coherent atomics (no backoff): ~60-80MB traffic + ~100us per sync
// (R7 front: 670us, 614MB, VALUBusy 2.9%).  R3/R6: front on <=32 blocks is a
// serial latency chain.  R4 (wide plain kernels): best total 1096, chain 650.
// Fix here: hipLaunchCooperativeKernel for guaranteed co-residency, but a
// CUSTOM barrier: 1 poller/block, s_sleep(32) backoff (~0.85us), threadfence
// release/acquire, counters zeroed by the PRECEDING kernel (no init race).
//   L1 k_emb_prep (1280 blk, R4 verbatim + zero barrier slots)
//   L2 k_front    (coop 128x512: A|F|A|F, 3 cheap barriers)
//   L3 k_chain    (16 blk, R4 body + latent/gi0 prologue in LDS)
//   L4 k_epi      (1028 blk, verbatim)
// Chain math unchanged: int8 M (per-row scale) x int8 h broadcast via
// mfma_i32_16x16x64_i8, parity-split gates, exact int32 accumulate.
// ---------------------------------------------------------------------------

typedef unsigned int uint_t;
typedef int v4i __attribute__((ext_vector_type(4)));

// ---- workspace layout (4-byte slot indices) ----
static constexpr size_t WS_HB   = 0;        // 16*16*256
static constexpr size_t WS_BAR  = 65536;    // 4 barrier counters (old QKV area)
static constexpr size_t WS_AO   = 262144;   // 16*16*256
static constexpr size_t WS_CV   = 606208;   // 1024 fused-bias consts
static constexpr size_t WS_MS   = 607232;   // 1024 per-row scales
static constexpr size_t WS_M8   = 608256;   // 1024*64 dwords packed int8 M
static constexpr size_t WS_HSEQ = 673792;   // 1028*16*256 floats

__device__ inline float sigf(float x){
    return __builtin_amdgcn_rcpf(1.0f + __builtin_amdgcn_exp2f(-1.442695041f*x));
}
__device__ inline float tanh_fast(float x){
    return 1.0f - 2.0f*__builtin_amdgcn_rcpf(1.0f + __builtin_amdgcn_exp2f(2.885390082f*x));
}

// custom grid barrier: release-fence, one atomic arrive per block, backoff
// poll by thread 0 only, acquire-fence.  Counter slot must be 0 at entry
// (zeroed by the previous kernel in the stream).
__device__ inline void gbar(uint_t* bar, int tid){
    __syncthreads();
    if(tid==0){
        __threadfence();                      // release: writeback this XCD L2
        atomicAdd(bar, 1u);                   // device-scope arrive
        while(__hip_atomic_load(bar, __ATOMIC_RELAXED,
                                __HIP_MEMORY_SCOPE_AGENT) < 128u)
            __builtin_amdgcn_s_sleep(32);     // ~2K cyc between polls
        __threadfence();                      // acquire
    }
    __syncthreads();
}

// ======================= embed + prepm (plain, wide — R4 verbatim) =========
// blocks 0..255: embed row bs; blocks 256..1279: prepm row r = bx-256.
// block 0 additionally zeroes the k_front barrier slots.

__global__ __launch_bounds__(256) void k_emb_prep(
    const float* gs, const float* eW, const float* eb,
    const float* Wih, const float* Whh, const float* bih, const float* bhh,
    const float* outW, const float* outb, float* ws)
{
    __shared__ float wrow[256]; __shared__ float red[256];
    __shared__ signed char q8[256];

    if(blockIdx.x < 256){
        if(blockIdx.x==0 && threadIdx.x<4)
            ((uint_t*)ws)[WS_BAR + threadIdx.x] = 0u;
        int bs = blockIdx.x;
        int i  = threadIdx.x;
        const float* g = gs + bs*16;
        float acc = eb[i];
#pragma unroll
        for(int d=0; d<16; ++d) acc += g[d]*eW[i*16+d];
        ws[WS_HB + (size_t)bs*256 + i] = acc;
        return;
    }

    int r = blockIdx.x - 256, c = threadIdx.x;
    bool hasA = (r<768);
    wrow[c] = hasA ? Wih[(size_t)r*256+c] : 0.0f;
    __syncthreads();
    float m;
    if(hasA){
        float a=0.f;
        for(int k=0;k<256;++k) a += wrow[k]*outW[(size_t)k*256+c];
        if(r<512) a += Whh[(size_t)r*256+c];
        m=a;
    } else {
        m = Whh[(size_t)(r-256)*256+c];
    }
    red[c] = wrow[c]*outb[c];
    __syncthreads();
    for(int off=128;off>0;off>>=1){ if(c<off) red[c]+=red[c+off]; __syncthreads(); }
    if(c==0){
        float cv;
        if(r<512)       cv = red[0] + bih[r] + bhh[r];
        else if(r<768)  cv = red[0] + bih[r];
        else            cv = bhh[r-256];
        ws[WS_CV + r] = cv;
    }
    __syncthreads();
    red[c] = fabsf(m);
    __syncthreads();
    for(int off=128;off>0;off>>=1){ if(c<off) red[c]=fmaxf(red[c],red[c+off]); __syncthreads(); }
    float rowmax = red[0];
    float inv = rowmax>0.f ? 127.0f/rowmax : 0.0f;
    q8[c] = (signed char)__float2int_rn(m*inv);
    if(c==0) ws[WS_MS + r] = rowmax>0.f ? rowmax*(1.0f/(127.0f*127.0f)) : 0.0f;
    __syncthreads();
    if(c<64){
        uint_t u = ((uint_t)(unsigned char)q8[4*c  ])
                 | ((uint_t)(unsigned char)q8[4*c+1] << 8)
                 | ((uint_t)(unsigned char)q8[4*c+2] << 16)
                 | ((uint_t)(unsigned char)q8[4*c+3] << 24);
        ((uint_t*)ws)[WS_M8 + (size_t)r*64 + c] = u;
    }
}

// ======================= co-resident front: A|F|A|F ========================
// 128 blocks x 512.  A phase: blocks 0-63 as (b,head), blocks 64-127 wait at
// the cheap barrier (~10us, backoff poll -> negligible traffic).  F phase:
// all 128 blocks, 2 tokens each.  3 custom barriers, no cg::grid.sync.

__global__ __launch_bounds__(512) void k_front(
    const float* qkvW, const float* qkvb,
    const float* aoW, const float* aob,
    const float* g1, const float* b1, const float* g2, const float* b2v,
    const float* W1, const float* fb1, const float* W2, const float* fb2,
    float* ws)
{
    __shared__ float s_h[16][256];            // 16 KB staging
    __shared__ float s_qkv[3][16][64];        // 12 KB q/k/v
    __shared__ float s_sc[16][16];            // scores
    __shared__ float s_f1[2][1024];           // F1 rows
    __shared__ float s_red[2][256];           // LN partials

    int tid = threadIdx.x;
    int bx  = blockIdx.x;
    uint_t* bar = (uint_t*)ws + WS_BAR;

    for(int l=0; l<2; ++l){
        if(bx < 64){
            // ============ A: qkv + attention, (b,head) ============
            int b = bx>>2, hh = bx&3;
            for(int u=tid; u<4096; u+=512)
                s_h[u>>8][u&255] = ws[WS_HB + (size_t)(b*16+(u>>8))*256 + (u&255)];
            __syncthreads();
            if(tid<192){
                int p = tid>>6, d = tid&63;           // p: 0=q 1=k 2=v
                int row = l*768 + p*256 + hh*64 + d;
                const float* wr = qkvW + (size_t)row*256;
                float bias = qkvb[row];
                float acc[16];
#pragma unroll
                for(int s=0;s<16;++s) acc[s]=bias;
                for(int k=0;k<256;k+=4){
                    float4 w4 = *(const float4*)(wr+k);
#pragma unroll
                    for(int s=0;s<16;++s){
                        float4 h4 = *(const float4*)&s_h[s][k];
                        acc[s] += w4.x*h4.x + w4.y*h4.y + w4.z*h4.z + w4.w*h4.w;
                    }
                }
#pragma unroll
                for(int s=0;s<16;++s) s_qkv[p][s][d] = acc[s];
            }
            __syncthreads();
            if(tid<256){
                int s = tid>>4, t = tid&15;
                float a=0.f;
#pragma unroll
                for(int d=0; d<64; ++d) a += s_qkv[0][s][d]*s_qkv[1][t][d];
                s_sc[s][t] = a*0.125f;
            }
            __syncthreads();
            if(tid<16){
                int r=tid;
                float m=-1e30f;
#pragma unroll
                for(int tt=0;tt<16;++tt) m=fmaxf(m,s_sc[r][tt]);
                float e[16]; float sum=0.f;
#pragma unroll
                for(int tt=0;tt<16;++tt){ e[tt]=__expf(s_sc[r][tt]-m); sum+=e[tt]; }
                float inv=1.0f/sum;
#pragma unroll
                for(int tt=0;tt<16;++tt) s_sc[r][tt]=e[tt]*inv;
            }
            __syncthreads();
            for(int u=tid; u<1024; u+=512){
                int s=u>>6, d=u&63;
                float o=0.f;
#pragma unroll
                for(int t2=0;t2<16;++t2) o += s_sc[s][t2]*s_qkv[2][t2][d];
                ws[WS_AO + (size_t)(b*16+s)*256 + hh*64 + d] = o;
            }
        }
        gbar(bar + 2*l, tid);                 // AO (and prev HB) visible

        // ============ F: ao + LN1 + ffn1 + ffn2 + LN2 (2 tokens) ============
        {
            int tk = tid>>8, i = tid&255;
            int bs = bx*2 + tk;
            s_h[tk][i] = ws[WS_AO + (size_t)bs*256 + i];
            float hb = ws[WS_HB + (size_t)bs*256 + i];
            __syncthreads();
            const float* wr = aoW + (size_t)(l*256+i)*256;
            float acc = aob[l*256+i];
            for(int k=0;k<256;k+=4){
                float4 w4 = *(const float4*)(wr+k);
                float4 h4 = *(const float4*)&s_h[tk][k];
                acc += w4.x*h4.x + w4.y*h4.y + w4.z*h4.z + w4.w*h4.w;
            }
            float x = hb + acc;
            // LN1
            s_red[tk][i]=x; __syncthreads();
            for(int off=128;off>0;off>>=1){ if(i<off) s_red[tk][i]+=s_red[tk][i+off]; __syncthreads(); }
            float mn = s_red[tk][0]*(1.0f/256.0f); __syncthreads();
            float d = x-mn;
            s_red[tk][i]=d*d; __syncthreads();
            for(int off=128;off>0;off>>=1){ if(i<off) s_red[tk][i]+=s_red[tk][i+off]; __syncthreads(); }
            float vv = s_red[tk][0]*(1.0f/256.0f);
            float h1 = (d / sqrtf(vv+1e-5f))*g1[l*256+i] + b1[l*256+i];
            __syncthreads();
            s_h[2+tk][i] = h1;
            __syncthreads();
            // ffn1
#pragma unroll
            for(int jj=0;jj<4;++jj){
                int j = jj*256 + i;
                const float* w1r = W1 + (size_t)(l*1024+j)*256;
                float a1 = fb1[l*1024+j];
                for(int k=0;k<256;k+=4){
                    float4 w4 = *(const float4*)(w1r+k);
                    float4 h4 = *(const float4*)&s_h[2+tk][k];
                    a1 += w4.x*h4.x + w4.y*h4.y + w4.z*h4.z + w4.w*h4.w;
                }
                s_f1[tk][j] = fmaxf(a1, 0.0f);
            }
            __syncthreads();
            // ffn2
            const float* w2r = W2 + (size_t)(l*256+i)*1024;
            float a2 = fb2[l*256+i];
            for(int k=0;k<1024;k+=4){
                float4 w4 = *(const float4*)(w2r+k);
                float4 h4 = *(const float4*)&s_f1[tk][k];
                a2 += w4.x*h4.x + w4.y*h4.y + w4.z*h4.z + w4.w*h4.w;
            }
            float x2 = h1 + a2;
            // LN2
            s_red[tk][i]=x2; __syncthreads();
            for(int off=128;off>0;off>>=1){ if(i<off) s_red[tk][i]+=s_red[tk][i+off]; __syncthreads(); }
            float mn2 = s_red[tk][0]*(1.0f/256.0f); __syncthreads();
            float d2 = x2-mn2;
            s_red[tk][i]=d2*d2; __syncthreads();
            for(int off=128;off>0;off>>=1){ if(i<off) s_red[tk][i]+=s_red[tk][i+off]; __syncthreads(); }
            float vv2 = s_red[tk][0]*(1.0f/256.0f);
            float y2 = d2 / sqrtf(vv2+1e-5f);
            ws[WS_HB + (size_t)bs*256 + i] = y2*g2[l*256+i] + b2v[l*256+i];
        }
        if(l==0) gbar(bar + 1, tid);          // HB(l0) visible for A(l1)
        // after F(l=1): kernel boundary provides visibility for k_chain
    }
}

// ======================= sequential GRU chain (R4 body + LG prologue) ======
// 16 blocks, 512 thr = 8 waves.  Prologue: latent mean + gi0 into LDS
// (replaces the separate lat_gi0 launch; identical op order).  Then R4 body:
// wave w owns h slice [w*32,w*32+32): 8 B-fragments x 4 K-tiles of
// mfma_i32_16x16x64_i8; A = h broadcast; parity-split gates.

__global__ __launch_bounds__(512,2) void k_chain(const float* Wih, const float* bih,
                                                 const float* bhh, float* ws){
    __shared__ alignas(16) signed char h8[2][256];
    __shared__ float latl[256];
    __shared__ float gi0l[768];
    int tid = threadIdx.x;
    int b   = blockIdx.x;
    int l   = tid & 63;
    int w   = tid >> 6;
    int col = l & 15;
    int grp = l >> 4;
    int par = grp & 1;
    int ge  = w*32 + par*16 + col;

    // ---- latent + gi0 prologue (LDS) ----
    if(tid<256){
        float a=0.f;
#pragma unroll
        for(int s=0;s<16;++s) a += ws[WS_HB + (size_t)(b*16+s)*256 + tid];
        latl[tid] = a*(1.0f/16.0f);
    }
    __syncthreads();
    for(int j=tid; j<768; j+=512){
        const float* wr = Wih + (size_t)j*256;
        float a = bih[j];
        for(int k=0;k<256;k+=4){
            float4 w4=*(const float4*)(wr+k);
            float4 l4=*(const float4*)&latl[k];
            a += w4.x*l4.x + w4.y*l4.y + w4.z*l4.z + w4.w*l4.w;
        }
        gi0l[j] = a;
    }
    __syncthreads();

    const uint_t* Mdw = (const uint_t*)ws + WS_M8;
    v4i wf[8][4];
#pragma unroll
    for(int s=0;s<4;++s){
#pragma unroll
        for(int half=0; half<2; ++half){
            int f = s*2 + half;
            int row = s*256 + w*32 + half*16 + col;
            const uint_t* src = Mdw + (size_t)row*64 + grp*4;
#pragma unroll
            for(int kt=0;kt<4;++kt)
                wf[f][kt] = *(const v4i*)(src + kt*16);
        }
    }
    float Cs[4], MSs[4];
#pragma unroll
    for(int s=0;s<4;++s){
        int row = s*256 + ge;
        Cs[s]  = ws[WS_CV + row];
        MSs[s] = ws[WS_MS + row];
    }

    float r0 = sigf(gi0l[ge]     + bhh[ge]);
    float z0 = sigf(gi0l[256+ge] + bhh[256+ge]);
    float n0 = tanh_fast(gi0l[512+ge] + r0*bhh[512+ge]);
    float hp = (1.0f-z0)*n0;

    float* hsp = ws + WS_HSEQ + (size_t)b*256;
    if(grp < 2){
        h8[0][w*32 + (l&31)] = (signed char)__float2int_rn(hp*127.0f);
        hsp[w*32 + (l&31)] = hp;
    }
    asm volatile("s_waitcnt lgkmcnt(0)" ::: "memory");
    __builtin_amdgcn_s_barrier();
    asm volatile("" ::: "memory");

    const v4i vzero = {0,0,0,0};
    int po = 0;
    for(int t=1; t<1028; ++t){
        hsp += 4096;
        v4i af[4];
#pragma unroll
        for(int kt=0;kt<4;++kt)
            af[kt] = *(const v4i*)&h8[po][kt*64 + grp*16];
        v4i acc[8];
#pragma unroll
        for(int f=0;f<8;++f){
            acc[f] = __builtin_amdgcn_mfma_i32_16x16x64_i8(af[0], wf[f][0], vzero, 0,0,0);
#pragma unroll
            for(int kt=1;kt<4;++kt)
                acc[f] = __builtin_amdgcn_mfma_i32_16x16x64_i8(af[kt], wf[f][kt], acc[f], 0,0,0);
        }
        int a_r = par ? acc[1][0] : acc[0][0];
        int a_z = par ? acc[3][0] : acc[2][0];
        int a_n = par ? acc[5][0] : acc[4][0];
        int a_h = par ? acc[7][0] : acc[6][0];
        float yr = MSs[0]*(float)a_r + Cs[0];
        float yz = MSs[1]*(float)a_z + Cs[1];
        float yn = MSs[2]*(float)a_n + Cs[2];
        float yh = MSs[3]*(float)a_h + Cs[3];
        float rr = sigf(yr);
        float zz = sigf(yz);
        float nn = tanh_fast(yn + rr*yh);
        hp = (1.0f-zz)*nn + zz*hp;
        if(grp < 2){
            h8[po^1][w*32 + (l&31)] = (signed char)__float2int_rn(hp*127.0f);
            hsp[w*32 + (l&31)] = hp;
        }
        asm volatile("s_waitcnt lgkmcnt(0)" ::: "memory");
        __builtin_amdgcn_s_barrier();
        asm volatile("" ::: "memory");
        po ^= 1;
    }
}

// ======================= epilogue GEMM (wide) ==============================
__global__ __launch_bounds__(256) void k_epi(const float* outW, const float* outb,
                                             const float* ws, float* out){
    __shared__ float ht[16][256];
    int t = blockIdx.x, j = threadIdx.x;
    for(int idx=j; idx<4096; idx+=256)
        ht[idx>>8][idx&255] = ws[WS_HSEQ + (size_t)t*4096 + idx];
    __syncthreads();
    const float* wr = outW + (size_t)j*256;
    float bias = outb[j];
    float acc[16];
#pragma unroll
    for(int bb=0;bb<16;++bb) acc[bb]=bias;
    for(int k=0;k<256;k+=4){
        float4 w4 = *(const float4*)(wr+k);
#pragma unroll
        for(int bb=0;bb<16;++bb)
            acc[bb] += w4.x*ht[bb][k]+w4.y*ht[bb][k+1]+w4.z*ht[bb][k+2]+w4.w*ht[bb][k+3];
    }
#pragma unroll
    for(int bb=0;bb<16;++bb)
        out[(size_t)bb*263168 + (size_t)t*256 + j] = acc[bb];
}

// ======================= launch ============================================

extern "C" void kernel_launch(void* const* d_in, const int* in_sizes, int n_in,
                              void* d_out, int out_size, void* d_ws, size_t ws_size,
                              hipStream_t stream){
    const float* gs   = (const float*)d_in[0];
    const float* eW   = (const float*)d_in[1];
    const float* eb   = (const float*)d_in[2];
    const float* qkvW = (const float*)d_in[3];
    const float* qkvb = (const float*)d_in[4];
    const float* aoW  = (const float*)d_in[5];
    const float* aob  = (const float*)d_in[6];
    const float* g1   = (const float*)d_in[7];
    const float* b1   = (const float*)d_in[8];
    const float* g2   = (const float*)d_in[9];
    const float* b2   = (const float*)d_in[10];
    const float* W1   = (const float*)d_in[11];
    const float* fb1  = (const float*)d_in[12];
    const float* W2   = (const float*)d_in[13];
    const float* fb2  = (const float*)d_in[14];
    const float* Wih  = (const float*)d_in[15];
    const float* Whh  = (const float*)d_in[16];
    const float* bih  = (const float*)d_in[17];
    const float* bhh  = (const float*)d_in[18];
    const float* outW = (const float*)d_in[19];
    const float* outb = (const float*)d_in[20];
    float* ws  = (float*)d_ws;
    float* out = (float*)d_out;

    k_emb_prep<<<1280,256,0,stream>>>(gs,eW,eb,Wih,Whh,bih,bhh,outW,outb,ws);

    void* args[] = {
        (void*)&qkvW, (void*)&qkvb, (void*)&aoW, (void*)&aob,
        (void*)&g1, (void*)&b1, (void*)&g2, (void*)&b2,
        (void*)&W1, (void*)&fb1, (void*)&W2, (void*)&fb2, (void*)&ws
    };
    hipLaunchCooperativeKernel((const void*)k_front, dim3(128), dim3(512),
                               args, 0, stream);

    k_chain<<<16,512,0,stream>>>(Wih,bih,bhh,ws);
    k_epi  <<<1028,256,0,stream>>>(outW,outb,ws,out);
}

// Round 9
// 1088.410 us; speedup vs baseline: 2.7996x; 1.3287x over previous
//
#include <hip/hip_runtime.h>

// ---------------------------------------------------------------------------
// GenomeDecoder, R11: consolidation on the proven R4 skeleton, 6 launches.
// Evidence ledger: R4 (8 plain wide launches) = 1096, best.  R5-R8 proved
// co-resident grid sync is structurally expensive on MI355X: device-scope
// acquire/release fences invalidate per-XCD L2 -> weight refetch storms
// (R7: 219MB FETCH), for cg::grid.sync AND custom backoff barriers alike.
// Kernel boundaries are the cheap fence here.  Chain is at its mapping's
// roofline: 64 MFMA/SIMD/step x ~20.4cyc = 1306 of 1520 cyc/step (86%);
// B-coverage invariant blocks within-CU gains; cross-CU N-split costs
// ~700-900cyc/step in fences = wash.
// Changes vs R4 (each boundary-saving, zero new sync):
//   1. embed folded INTO qkv_attn(l0) blocks (in-LDS, head0 writes HB) and
//      prepm rides as blocks 64-1087 of the same launch  (-2 launches)
//   2. lat+gi0 folded into k_chain prologue (R8-verified)  (-1 launch)
// Chain math unchanged: int8 M (per-row scale) x int8 h broadcast via
// mfma_i32_16x16x64_i8, parity-split gates, exact int32 accumulate.
// ---------------------------------------------------------------------------

typedef unsigned int uint_t;
typedef int v4i __attribute__((ext_vector_type(4)));

// ---- workspace layout (4-byte slot indices) ----
static constexpr size_t WS_HB   = 0;        // 16*16*256
static constexpr size_t WS_AO   = 262144;   // 16*16*256
static constexpr size_t WS_CV   = 606208;   // 1024 fused-bias consts
static constexpr size_t WS_MS   = 607232;   // 1024 per-row scales
static constexpr size_t WS_M8   = 608256;   // 1024*64 dwords packed int8 M
static constexpr size_t WS_HSEQ = 673792;   // 1028*16*256 floats

__device__ inline float sigf(float x){
    return __builtin_amdgcn_rcpf(1.0f + __builtin_amdgcn_exp2f(-1.442695041f*x));
}
__device__ inline float tanh_fast(float x){
    return 1.0f - 2.0f*__builtin_amdgcn_rcpf(1.0f + __builtin_amdgcn_exp2f(2.885390082f*x));
}

// ============== L1: [embed+qkv+attn l0] (blocks 0-63) || prepm (64-1087) ===

__global__ __launch_bounds__(256) void k_pre(
    const float* gs, const float* eW, const float* eb,
    const float* qkvW, const float* qkvb,
    const float* Wih, const float* Whh, const float* bih, const float* bhh,
    const float* outW, const float* outb, float* ws)
{
    __shared__ float s_h[16][256];
    __shared__ float s_qkv[3][16][64];
    __shared__ float s_sc[16][16];

    int tid = threadIdx.x;

    if(blockIdx.x >= 64){
        // ---------------- prepm row r (R4 verbatim) ----------------
        __shared__ float wrow[256]; __shared__ float red[256];
        __shared__ signed char q8[256];
        int r = blockIdx.x - 64, c = tid;
        bool hasA = (r<768);
        wrow[c] = hasA ? Wih[(size_t)r*256+c] : 0.0f;
        __syncthreads();
        float m;
        if(hasA){
            float a=0.f;
            for(int k=0;k<256;++k) a += wrow[k]*outW[(size_t)k*256+c];
            if(r<512) a += Whh[(size_t)r*256+c];
            m=a;
        } else {
            m = Whh[(size_t)(r-256)*256+c];
        }
        red[c] = wrow[c]*outb[c];
        __syncthreads();
        for(int off=128;off>0;off>>=1){ if(c<off) red[c]+=red[c+off]; __syncthreads(); }
        if(c==0){
            float cv;
            if(r<512)       cv = red[0] + bih[r] + bhh[r];
            else if(r<768)  cv = red[0] + bih[r];
            else            cv = bhh[r-256];
            ws[WS_CV + r] = cv;
        }
        __syncthreads();
        red[c] = fabsf(m);
        __syncthreads();
        for(int off=128;off>0;off>>=1){ if(c<off) red[c]=fmaxf(red[c],red[c+off]); __syncthreads(); }
        float rowmax = red[0];
        float inv = rowmax>0.f ? 127.0f/rowmax : 0.0f;
        q8[c] = (signed char)__float2int_rn(m*inv);
        if(c==0) ws[WS_MS + r] = rowmax>0.f ? rowmax*(1.0f/(127.0f*127.0f)) : 0.0f;
        __syncthreads();
        if(c<64){
            uint_t u = ((uint_t)(unsigned char)q8[4*c  ])
                     | ((uint_t)(unsigned char)q8[4*c+1] << 8)
                     | ((uint_t)(unsigned char)q8[4*c+2] << 16)
                     | ((uint_t)(unsigned char)q8[4*c+3] << 24);
            ((uint_t*)ws)[WS_M8 + (size_t)r*64 + c] = u;
        }
        return;
    }

    // ---------------- embed (inline) + qkv + attention, (b,head), l=0 ------
    int b = blockIdx.x>>2, hh = blockIdx.x&3;

    {   // embed: thread i computes dim i for all 16 tokens of batch b
        int i = tid;
        float ew[16];
#pragma unroll
        for(int d=0;d<16;++d) ew[d] = eW[i*16+d];
        float bias = eb[i];
#pragma unroll
        for(int s=0;s<16;++s){
            const float* g = gs + (b*16+s)*16;
            float acc = bias;
#pragma unroll
            for(int d=0;d<16;++d) acc += g[d]*ew[d];
            s_h[s][i] = acc;
            if(hh==0) ws[WS_HB + (size_t)(b*16+s)*256 + i] = acc;
        }
    }
    __syncthreads();

    if(tid<192){
        int p = tid>>6, d = tid&63;           // p: 0=q 1=k 2=v
        int row = p*256 + hh*64 + d;          // l=0
        const float* wr = qkvW + (size_t)row*256;
        float bias = qkvb[row];
        float acc[16];
#pragma unroll
        for(int s=0;s<16;++s) acc[s]=bias;
        for(int k=0;k<256;k+=4){
            float4 w4 = *(const float4*)(wr+k);
#pragma unroll
            for(int s=0;s<16;++s){
                float4 h4 = *(const float4*)&s_h[s][k];
                acc[s] += w4.x*h4.x + w4.y*h4.y + w4.z*h4.z + w4.w*h4.w;
            }
        }
#pragma unroll
        for(int s=0;s<16;++s) s_qkv[p][s][d] = acc[s];
    }
    __syncthreads();
    {
        int s = tid>>4, t = tid&15;
        float a=0.f;
#pragma unroll
        for(int d=0; d<64; ++d) a += s_qkv[0][s][d]*s_qkv[1][t][d];
        s_sc[s][t] = a*0.125f;
    }
    __syncthreads();
    if(tid<16){
        int r=tid;
        float m=-1e30f;
#pragma unroll
        for(int tt=0;tt<16;++tt) m=fmaxf(m,s_sc[r][tt]);
        float e[16]; float sum=0.f;
#pragma unroll
        for(int tt=0;tt<16;++tt){ e[tt]=__expf(s_sc[r][tt]-m); sum+=e[tt]; }
        float inv=1.0f/sum;
#pragma unroll
        for(int tt=0;tt<16;++tt) s_sc[r][tt]=e[tt]*inv;
    }
    __syncthreads();
    for(int u=tid; u<1024; u+=256){
        int s=u>>6, d=u&63;
        float o=0.f;
#pragma unroll
        for(int t2=0;t2<16;++t2) o += s_sc[s][t2]*s_qkv[2][t2][d];
        ws[WS_AO + (size_t)(b*16+s)*256 + hh*64 + d] = o;
    }
}

// ======================= qkv + attention (layer 1) =========================

__global__ __launch_bounds__(256) void k_qkv_attn(const float* qkvW, const float* qkvb,
                                                  float* ws, int l){
    __shared__ float s_h[16][256];
    __shared__ float s_q[16][64], s_k[16][64], s_v[16][64];
    __shared__ float s_sc[16][16];
    int b = blockIdx.x>>2, hh = blockIdx.x&3;
    int tid = threadIdx.x;

    for(int u=tid; u<4096; u+=256)
        s_h[u>>8][u&255] = ws[WS_HB + (size_t)(b*16+(u>>8))*256 + (u&255)];
    __syncthreads();

    if(tid<192){
        int p = tid>>6, d = tid&63;
        int row = l*768 + p*256 + hh*64 + d;
        const float* wr = qkvW + (size_t)row*256;
        float bias = qkvb[row];
        float acc[16];
#pragma unroll
        for(int s=0;s<16;++s) acc[s]=bias;
        for(int k=0;k<256;k+=4){
            float4 w4 = *(const float4*)(wr+k);
#pragma unroll
            for(int s=0;s<16;++s){
                float4 h4 = *(const float4*)&s_h[s][k];
                acc[s] += w4.x*h4.x + w4.y*h4.y + w4.z*h4.z + w4.w*h4.w;
            }
        }
        float (*dst)[64] = (p==0) ? s_q : (p==1) ? s_k : s_v;
#pragma unroll
        for(int s=0;s<16;++s) dst[s][d] = acc[s];
    }
    __syncthreads();
    {
        int s = tid>>4, t = tid&15;
        float a=0.f;
#pragma unroll
        for(int d=0; d<64; ++d) a += s_q[s][d]*s_k[t][d];
        s_sc[s][t] = a*0.125f;
    }
    __syncthreads();
    if(tid<16){
        int r=tid;
        float m=-1e30f;
#pragma unroll
        for(int tt=0;tt<16;++tt) m=fmaxf(m,s_sc[r][tt]);
        float e[16]; float sum=0.f;
#pragma unroll
        for(int tt=0;tt<16;++tt){ e[tt]=__expf(s_sc[r][tt]-m); sum+=e[tt]; }
        float inv=1.0f/sum;
#pragma unroll
        for(int tt=0;tt<16;++tt) s_sc[r][tt]=e[tt]*inv;
    }
    __syncthreads();
    for(int u=tid; u<1024; u+=256){
        int s=u>>6, d=u&63;
        float o=0.f;
#pragma unroll
        for(int t2=0;t2<16;++t2) o += s_sc[s][t2]*s_v[t2][d];
        ws[WS_AO + (size_t)(b*16+s)*256 + hh*64 + d] = o;
    }
}

// ============ attn-out + LN1 + ffn1 + ffn2 + LN2, per (b,s) ================

__global__ __launch_bounds__(256) void k_ao_ffn(
    const float* aoW, const float* aob, const float* g1, const float* b1,
    const float* W1, const float* fb1, const float* W2, const float* fb2,
    const float* g2, const float* b2v, float* ws, int l)
{
    __shared__ float s_x[256];
    __shared__ float s_f1[1024];
    __shared__ float red[256];
    int bs = blockIdx.x, i = threadIdx.x;

    s_x[i] = ws[WS_AO + (size_t)bs*256 + i];
    float hb = ws[WS_HB + (size_t)bs*256 + i];
    __syncthreads();

    const float* wr = aoW + (size_t)(l*256+i)*256;
    float acc = aob[l*256+i];
    for(int k=0;k<256;k+=4){
        float4 w4 = *(const float4*)(wr+k);
        float4 h4 = *(const float4*)&s_x[k];
        acc += w4.x*h4.x + w4.y*h4.y + w4.z*h4.z + w4.w*h4.w;
    }
    float x = hb + acc;
    red[i]=x; __syncthreads();
    for(int off=128;off>0;off>>=1){ if(i<off) red[i]+=red[i+off]; __syncthreads(); }
    float mn = red[0]*(1.0f/256.0f); __syncthreads();
    float d = x-mn;
    red[i]=d*d; __syncthreads();
    for(int off=128;off>0;off>>=1){ if(i<off) red[i]+=red[i+off]; __syncthreads(); }
    float vv = red[0]*(1.0f/256.0f);
    float h1 = (d / sqrtf(vv+1e-5f))*g1[l*256+i] + b1[l*256+i];
    __syncthreads();
    s_x[i] = h1;
    __syncthreads();

#pragma unroll
    for(int jj=0;jj<4;++jj){
        int j = jj*256 + i;
        const float* w1r = W1 + (size_t)(l*1024+j)*256;
        float a1 = fb1[l*1024+j];
        for(int k=0;k<256;k+=4){
            float4 w4 = *(const float4*)(w1r+k);
            float4 h4 = *(const float4*)&s_x[k];
            a1 += w4.x*h4.x + w4.y*h4.y + w4.z*h4.z + w4.w*h4.w;
        }
        s_f1[j] = fmaxf(a1, 0.0f);
    }
    __syncthreads();

    const float* w2r = W2 + (size_t)(l*256+i)*1024;
    float a2 = fb2[l*256+i];
    for(int k=0;k<1024;k+=4){
        float4 w4 = *(const float4*)(w2r+k);
        float4 h4 = *(const float4*)&s_f1[k];
        a2 += w4.x*h4.x + w4.y*h4.y + w4.z*h4.z + w4.w*h4.w;
    }
    float x2 = h1 + a2;
    red[i]=x2; __syncthreads();
    for(int off=128;off>0;off>>=1){ if(i<off) red[i]+=red[i+off]; __syncthreads(); }
    float mn2 = red[0]*(1.0f/256.0f); __syncthreads();
    float d2 = x2-mn2;
    red[i]=d2*d2; __syncthreads();
    for(int off=128;off>0;off>>=1){ if(i<off) red[i]+=red[i+off]; __syncthreads(); }
    float vv2 = red[0]*(1.0f/256.0f);
    float y2 = d2 / sqrtf(vv2+1e-5f);
    ws[WS_HB + (size_t)bs*256 + i] = y2*g2[l*256+i] + b2v[l*256+i];
}

// ======================= GRU chain (R8-verified, lat/gi0 prologue) =========

__global__ __launch_bounds__(512,2) void k_chain(const float* Wih, const float* bih,
                                                 const float* bhh, float* ws){
    __shared__ alignas(16) signed char h8[2][256];
    __shared__ float latl[256];
    __shared__ float gi0l[768];
    int tid = threadIdx.x;
    int b   = blockIdx.x;
    int l   = tid & 63;
    int w   = tid >> 6;
    int col = l & 15;
    int grp = l >> 4;
    int par = grp & 1;
    int ge  = w*32 + par*16 + col;

    // ---- latent + gi0 prologue (LDS) ----
    if(tid<256){
        float a=0.f;
#pragma unroll
        for(int s=0;s<16;++s) a += ws[WS_HB + (size_t)(b*16+s)*256 + tid];
        latl[tid] = a*(1.0f/16.0f);
    }
    __syncthreads();
    for(int j=tid; j<768; j+=512){
        const float* wr = Wih + (size_t)j*256;
        float a = bih[j];
        for(int k=0;k<256;k+=4){
            float4 w4=*(const float4*)(wr+k);
            float4 l4=*(const float4*)&latl[k];
            a += w4.x*l4.x + w4.y*l4.y + w4.z*l4.z + w4.w*l4.w;
        }
        gi0l[j] = a;
    }
    __syncthreads();

    const uint_t* Mdw = (const uint_t*)ws + WS_M8;
    v4i wf[8][4];
#pragma unroll
    for(int s=0;s<4;++s){
#pragma unroll
        for(int half=0; half<2; ++half){
            int f = s*2 + half;
            int row = s*256 + w*32 + half*16 + col;
            const uint_t* src = Mdw + (size_t)row*64 + grp*4;
#pragma unroll
            for(int kt=0;kt<4;++kt)
                wf[f][kt] = *(const v4i*)(src + kt*16);
        }
    }
    float Cs[4], MSs[4];
#pragma unroll
    for(int s=0;s<4;++s){
        int row = s*256 + ge;
        Cs[s]  = ws[WS_CV + row];
        MSs[s] = ws[WS_MS + row];
    }

    float r0 = sigf(gi0l[ge]     + bhh[ge]);
    float z0 = sigf(gi0l[256+ge] + bhh[256+ge]);
    float n0 = tanh_fast(gi0l[512+ge] + r0*bhh[512+ge]);
    float hp = (1.0f-z0)*n0;

    float* hsp = ws + WS_HSEQ + (size_t)b*256;
    if(grp < 2){
        h8[0][w*32 + (l&31)] = (signed char)__float2int_rn(hp*127.0f);
        hsp[w*32 + (l&31)] = hp;
    }
    asm volatile("s_waitcnt lgkmcnt(0)" ::: "memory");
    __builtin_amdgcn_s_barrier();
    asm volatile("" ::: "memory");

    const v4i vzero = {0,0,0,0};
    int po = 0;
    for(int t=1; t<1028; ++t){
        hsp += 4096;
        v4i af[4];
#pragma unroll
        for(int kt=0;kt<4;++kt)
            af[kt] = *(const v4i*)&h8[po][kt*64 + grp*16];
        v4i acc[8];
#pragma unroll
        for(int f=0;f<8;++f){
            acc[f] = __builtin_amdgcn_mfma_i32_16x16x64_i8(af[0], wf[f][0], vzero, 0,0,0);
#pragma unroll
            for(int kt=1;kt<4;++kt)
                acc[f] = __builtin_amdgcn_mfma_i32_16x16x64_i8(af[kt], wf[f][kt], acc[f], 0,0,0);
        }
        int a_r = par ? acc[1][0] : acc[0][0];
        int a_z = par ? acc[3][0] : acc[2][0];
        int a_n = par ? acc[5][0] : acc[4][0];
        int a_h = par ? acc[7][0] : acc[6][0];
        float yr = MSs[0]*(float)a_r + Cs[0];
        float yz = MSs[1]*(float)a_z + Cs[1];
        float yn = MSs[2]*(float)a_n + Cs[2];
        float yh = MSs[3]*(float)a_h + Cs[3];
        float rr = sigf(yr);
        float zz = sigf(yz);
        float nn = tanh_fast(yn + rr*yh);
        hp = (1.0f-zz)*nn + zz*hp;
        if(grp < 2){
            h8[po^1][w*32 + (l&31)] = (signed char)__float2int_rn(hp*127.0f);
            hsp[w*32 + (l&31)] = hp;
        }
        asm volatile("s_waitcnt lgkmcnt(0)" ::: "memory");
        __builtin_amdgcn_s_barrier();
        asm volatile("" ::: "memory");
        po ^= 1;
    }
}

// ======================= epilogue GEMM (wide) ==============================

__global__ __launch_bounds__(256) void k_epi(const float* outW, const float* outb,
                                             const float* ws, float* out){
    __shared__ float ht[16][256];
    int t = blockIdx.x, j = threadIdx.x;
    for(int idx=j; idx<4096; idx+=256)
        ht[idx>>8][idx&255] = ws[WS_HSEQ + (size_t)t*4096 + idx];
    __syncthreads();
    const float* wr = outW + (size_t)j*256;
    float bias = outb[j];
    float acc[16];
#pragma unroll
    for(int bb=0;bb<16;++bb) acc[bb]=bias;
    for(int k=0;k<256;k+=4){
        float4 w4 = *(const float4*)(wr+k);
#pragma unroll
        for(int bb=0;bb<16;++bb)
            acc[bb] += w4.x*ht[bb][k]+w4.y*ht[bb][k+1]+w4.z*ht[bb][k+2]+w4.w*ht[bb][k+3];
    }
#pragma unroll
    for(int bb=0;bb<16;++bb)
        out[(size_t)bb*263168 + (size_t)t*256 + j] = acc[bb];
}

// ======================= launch ============================================

extern "C" void kernel_launch(void* const* d_in, const int* in_sizes, int n_in,
                              void* d_out, int out_size, void* d_ws, size_t ws_size,
                              hipStream_t stream){
    const float* gs   = (const float*)d_in[0];
    const float* eW   = (const float*)d_in[1];
    const float* eb   = (const float*)d_in[2];
    const float* qkvW = (const float*)d_in[3];
    const float* qkvb = (const float*)d_in[4];
    const float* aoW  = (const float*)d_in[5];
    const float* aob  = (const float*)d_in[6];
    const float* g1   = (const float*)d_in[7];
    const float* b1   = (const float*)d_in[8];
    const float* g2   = (const float*)d_in[9];
    const float* b2   = (const float*)d_in[10];
    const float* W1   = (const float*)d_in[11];
    const float* fb1  = (const float*)d_in[12];
    const float* W2   = (const float*)d_in[13];
    const float* fb2  = (const float*)d_in[14];
    const float* Wih  = (const float*)d_in[15];
    const float* Whh  = (const float*)d_in[16];
    const float* bih  = (const float*)d_in[17];
    const float* bhh  = (const float*)d_in[18];
    const float* outW = (const float*)d_in[19];
    const float* outb = (const float*)d_in[20];
    float* ws  = (float*)d_ws;
    float* out = (float*)d_out;

    k_pre     <<<1088,256,0,stream>>>(gs,eW,eb,qkvW,qkvb,Wih,Whh,bih,bhh,outW,outb,ws);
    k_ao_ffn  <<<256,256,0,stream>>>(aoW,aob,g1,b1,W1,fb1,W2,fb2,g2,b2,ws,0);
    k_qkv_attn<<<64,256,0,stream>>>(qkvW,qkvb,ws,1);
    k_ao_ffn  <<<256,256,0,stream>>>(aoW,aob,g1,b1,W1,fb1,W2,fb2,g2,b2,ws,1);
    k_chain   <<<16,512,0,stream>>>(Wih,bih,bhh,ws);
    k_epi     <<<1028,256,0,stream>>>(outW,outb,ws,out);
}